// Round 12
// baseline (1052.221 us; speedup 1.0000x reference)
//
#include <hip/hip_runtime.h>
#include <stdint.h>

#define BATCH 4096
#define FEAT  40960
#define H1    512
#define KS    4
#define KCHUNK (FEAT / KS)     // 10240
#define NT    (KCHUNK / 64)    // 160 K-tiles (BK=64) per block
#define NT64  (FEAT / 64)      // 640 global K-tiles
#define WIMG  65536            // bytes per global W K-tile image (512x64 bf16)
#define ABOFF 65536            // LDS: Wbuf0@0 Wbuf1@32768 Abuf0@65536 Abuf1@98304

typedef float f32x4 __attribute__((ext_vector_type(4)));
typedef short s16x8 __attribute__((ext_vector_type(8)));
typedef unsigned int u32x2 __attribute__((ext_vector_type(2)));
typedef unsigned int u32x4 __attribute__((ext_vector_type(4)));

// round-to-nearest-even f32 -> bf16, packed pair (lo in low 16 bits)
__device__ __forceinline__ unsigned bfpack2(float lo, float hi) {
  unsigned a = __float_as_uint(lo);
  unsigned b = __float_as_uint(hi);
  a += 0x7FFFu + ((a >> 16) & 1u);
  b += 0x7FFFu + ((b >> 16) & 1u);
  return (a >> 16) | (b & 0xFFFF0000u);
}

// legacy swizzle for fc kernel's 64B-row tiles
__device__ __forceinline__ int lds_swz(int r, int cb) {
  return (r << 6) + (cb ^ (((r >> 1) & 3) << 4));
}

// async global->LDS, 16B per lane; LDS dest = wave-uniform base + lane*16.
__device__ __forceinline__ void glds16(const void* g, void* l) {
  __builtin_amdgcn_global_load_lds(
      (const __attribute__((address_space(1))) unsigned*)g,
      (__attribute__((address_space(3))) unsigned*)l, 16, 0, 0);
}

#define PHASE_BAR()                    \
  do {                                 \
    __builtin_amdgcn_sched_barrier(0); \
    __builtin_amdgcn_s_barrier();      \
    __builtin_amdgcn_sched_barrier(0); \
  } while (0)

// ---------------------------------------------------------------------------
// Kernel 0: one-time ftw f32 -> bf16 fragment-major image per K-tile(64):
// off = T*65536 + (r>>8)*32768 + ((r>>4)&15)*2048 + (k/32)*1024
//       + (((k%32)/8)*16 + (r&15))*16 + (k%8)*2
// A block's per-tile slice (its 256 W rows) is a contiguous 32KB LDS image.
// ---------------------------------------------------------------------------
__global__ __launch_bounds__(512)
void wcvt_kernel(const float* __restrict__ ftw, char* __restrict__ wbf) {
  const int T = blockIdx.x;  // 0..NT64-1
  const int tid = threadIdx.x;
  const int c = tid & 7;     // k-octet: k = c*8..c*8+7 (one 16B fragment)
  const int r0 = tid >> 3;   // 64 rows per pass
#pragma unroll
  for (int pass = 0; pass < 8; ++pass) {
    const int r = pass * 64 + r0;
    const float* src = ftw + (size_t)r * FEAT + T * 64 + c * 8;
    f32x4 v0 = *(const f32x4*)src;
    f32x4 v1 = *(const f32x4*)(src + 4);
    u32x4 o;
    o.x = bfpack2(v0.x, v0.y); o.y = bfpack2(v0.z, v0.w);
    o.z = bfpack2(v1.x, v1.y); o.w = bfpack2(v1.z, v1.w);
    const int lane = (c & 3) * 16 + (r & 15);
    *(u32x4*)(wbf + (size_t)T * WIMG + (r >> 8) * 32768 +
              ((r >> 4) & 15) * 2048 + (c >> 2) * 1024 + lane * 16) = o;
  }
}

// ---------------------------------------------------------------------------
// Kernel 1: feature-transform GEMM, split-K partials. 256x256 / 8-PHASE-CLASS.
// BM=256 BN=256 BK=64, 512 thr = 8 waves (2M x 4N), wave out 128x64,
// acc[8][4] = 128 AGPR. LDS 128KB (W 2x32KB + A 2x32KB) -> 1 block/CU.
// BM=256 cuts W L2/L3 re-read traffic 4x vs the 513us 64-row plateau
// (5.4 GB -> 1.34 GB): arithmetic intensity was the binding constraint.
// Schedule: 4 phases/K-tile {vmcnt(8); barrier; ds_reads + stage-issue;
// lgkm0; setprio(1) 16xMFMA setprio(0)}; counted vmcnt never drains the
// pipeline (T3+T4); ledger at tile top = [W(t):4, A(t+1):8].
// ---------------------------------------------------------------------------
__global__ __launch_bounds__(512, 2)
void ft_gemm_kernel(const float* __restrict__ whiteF,
                    const float* __restrict__ blackF,
                    const char* __restrict__ wbf,
                    float* __restrict__ Ppart) {
  __shared__ char smem[131072];

  const int tid = threadIdx.x, bid = blockIdx.x;
  // XCD (bid&7) = (ks,nt): the 32 blocks per XCD share one 5MB W region.
  const int nt = bid & 1;
  const int ks = (bid >> 1) & 3;
  const int p  = (bid >> 3) & 1;
  const int mt = bid >> 4;  // 0..15

  const float* Ag =
      (p == 0 ? whiteF : blackF) + (size_t)(mt * 256) * FEAT + ks * KCHUNK;

  const int lane = tid & 63, wave = tid >> 6;
  const int wm = wave >> 2, wn = wave & 3;
  const int lrow = lane & 15, lkq = lane >> 4;
  const int rx7 = lrow & 7;

  // ---- A staging map: thread covers row=tid>>1, k-half h=tid&1 (32 f32)
  const int ar = tid >> 1, ah = tid & 1;
  const float* aptr = Ag + (size_t)ar * FEAT + ah * 32;
  int awr[4];  // ds_write addrs (chunk = ah*4+i, swizzled ^ (ar&7))
#pragma unroll
  for (int i = 0; i < 4; ++i)
    awr[i] = ar * 128 + (((ah * 4 + i) ^ (ar & 7)) << 4);

  // ---- A fragment read bases: frag m row = wm*128 + m*16 + lrow
  int ard[8];
#pragma unroll
  for (int m = 0; m < 8; ++m) ard[m] = (wm * 128 + m * 16 + lrow) * 128;
  const int co0 = (lkq ^ rx7) << 4;  // j0 chunk offset; j1 = co0 ^ 64

  // ---- W: image slice base (this block's n-tile), per-wave stage slices
  const char* wimg = wbf + (size_t)(ks * NT) * WIMG + nt * 32768;
  int wrd[4];  // read: cbl = wn*4+n
#pragma unroll
  for (int n = 0; n < 4; ++n) wrd[n] = (wn * 4 + n) * 2048 + lane * 16;
  // stage: wave owns cbl = wave*2+q
  const int ws0 = (wave * 2) * 2048 + lane * 16;

  f32x4 acc[8][4];
#pragma unroll
  for (int m = 0; m < 8; ++m)
#pragma unroll
    for (int n = 0; n < 4; ++n) acc[m][n] = (f32x4){0.f, 0.f, 0.f, 0.f};

  f32x4 rA[8];  // A(t+1) f32 stage regs (32 f32)

  // ---- prologue: A_ld(0); W(0)->Wbuf0; cvt A(0)->Abuf0; A_ld(1)
#pragma unroll
  for (int i = 0; i < 8; ++i) rA[i] = *(const f32x4*)(aptr + i * 4);
#pragma unroll
  for (int q = 0; q < 2; ++q)
#pragma unroll
    for (int j = 0; j < 2; ++j)
      glds16(wimg + ws0 + q * 2048 + j * 1024,
             smem + ws0 + q * 2048 + j * 1024 - lane * 16 + lane * 16);
  {  // cvt A(0): compiler auto-waits vmcnt(4) (A regs oldest; W(0) spared)
#pragma unroll
    for (int i = 0; i < 4; ++i) {
      u32x4 o;
      o.x = bfpack2(rA[2 * i].x, rA[2 * i].y);
      o.y = bfpack2(rA[2 * i].z, rA[2 * i].w);
      o.z = bfpack2(rA[2 * i + 1].x, rA[2 * i + 1].y);
      o.w = bfpack2(rA[2 * i + 1].z, rA[2 * i + 1].w);
      *(u32x4*)(smem + ABOFF + awr[i]) = o;
    }
  }
#pragma unroll
  for (int i = 0; i < 8; ++i) rA[i] = *(const f32x4*)(aptr + 64 + i * 4);
  asm volatile("s_waitcnt lgkmcnt(0)" ::: "memory");
  PHASE_BAR();
  // steady tile-top queue: [W(t):4, A(t+1):8]

#define GSTEP(B, t)                                                           \
  {                                                                           \
    const char* Wb = smem + (B) * 32768;                                      \
    const char* Ab = smem + ABOFF + (B) * 32768;                              \
    /* ---- P0: completes W(t); reads j0 m0-3 + W j0; stages W(t+1) */        \
    asm volatile("s_waitcnt vmcnt(8)" ::: "memory");                          \
    PHASE_BAR();                                                              \
    s16x8 af[4], wf[4];                                                       \
    _Pragma("unroll") for (int m = 0; m < 4; ++m)                             \
        af[m] = *(const s16x8*)(Ab + ard[m] + co0);                           \
    _Pragma("unroll") for (int n = 0; n < 4; ++n)                             \
        wf[n] = *(const s16x8*)(Wb + wrd[n]);                                 \
    {                                                                         \
      const int t1 = ((t) + 1 < NT) ? (t) + 1 : NT - 1;                       \
      const char* ws = wimg + (size_t)t1 * WIMG + ws0;                        \
      char* wd = smem + ((B) ^ 1) * 32768 + ws0 - 0;                          \
      _Pragma("unroll") for (int q = 0; q < 2; ++q)                           \
        _Pragma("unroll") for (int j = 0; j < 2; ++j)                         \
            glds16(ws + q * 2048 + j * 1024, wd + q * 2048 + j * 1024);       \
    }                                                                         \
    asm volatile("s_waitcnt lgkmcnt(0)" ::: "memory");                        \
    __builtin_amdgcn_sched_barrier(0);                                        \
    __builtin_amdgcn_s_setprio(1);                                            \
    _Pragma("unroll") for (int n = 0; n < 4; ++n)                             \
      _Pragma("unroll") for (int m = 0; m < 4; ++m)                           \
          acc[m][n] = __builtin_amdgcn_mfma_f32_16x16x32_bf16(                \
              af[m], wf[n], acc[m][n], 0, 0, 0);                              \
    __builtin_amdgcn_s_setprio(0);                                            \
    /* ---- P1: reads j0 m4-7; MFMA j0 m4-7 */                                \
    PHASE_BAR();                                                              \
    s16x8 ag[4];                                                              \
    _Pragma("unroll") for (int m = 0; m < 4; ++m)                             \
        ag[m] = *(const s16x8*)(Ab + ard[4 + m] + co0);                       \
    asm volatile("s_waitcnt lgkmcnt(0)" ::: "memory");                        \
    __builtin_amdgcn_sched_barrier(0);                                        \
    __builtin_amdgcn_s_setprio(1);                                            \
    _Pragma("unroll") for (int n = 0; n < 4; ++n)                             \
      _Pragma("unroll") for (int m = 0; m < 4; ++m)                           \
          acc[4 + m][n] = __builtin_amdgcn_mfma_f32_16x16x32_bf16(            \
              ag[m], wf[n], acc[4 + m][n], 0, 0, 0);                          \
    __builtin_amdgcn_s_setprio(0);                                            \
    /* ---- P2: cvt+write A(t+1) (auto vmcnt(4)); A_ld(t+2); j1 m0-3 */       \
    PHASE_BAR();                                                              \
    _Pragma("unroll") for (int i = 0; i < 4; ++i) {                           \
      u32x4 o;                                                                \
      o.x = bfpack2(rA[2 * i].x, rA[2 * i].y);                                \
      o.y = bfpack2(rA[2 * i].z, rA[2 * i].w);                                \
      o.z = bfpack2(rA[2 * i + 1].x, rA[2 * i + 1].y);                        \
      o.w = bfpack2(rA[2 * i + 1].z, rA[2 * i + 1].w);                        \
      *(u32x4*)(smem + ABOFF + ((B) ^ 1) * 32768 + awr[i]) = o;               \
    }                                                                         \
    {                                                                         \
      const int t2 = ((t) + 2 < NT) ? (t) + 2 : NT - 1;                       \
      _Pragma("unroll") for (int i = 0; i < 8; ++i)                           \
          rA[i] = *(const f32x4*)(aptr + (size_t)t2 * 64 + i * 4);            \
    }                                                                         \
    _Pragma("unroll") for (int n = 0; n < 4; ++n)                             \
        wf[n] = *(const s16x8*)(Wb + wrd[n] + 1024);                          \
    _Pragma("unroll") for (int m = 0; m < 4; ++m)                             \
        af[m] = *(const s16x8*)(Ab + ard[m] + (co0 ^ 64));                    \
    asm volatile("s_waitcnt lgkmcnt(0)" ::: "memory");                        \
    __builtin_amdgcn_sched_barrier(0);                                        \
    __builtin_amdgcn_s_setprio(1);                                            \
    _Pragma("unroll") for (int n = 0; n < 4; ++n)                             \
      _Pragma("unroll") for (int m = 0; m < 4; ++m)                           \
          acc[m][n] = __builtin_amdgcn_mfma_f32_16x16x32_bf16(                \
              af[m], wf[n], acc[m][n], 0, 0, 0);                              \
    __builtin_amdgcn_s_setprio(0);                                            \
    /* ---- P3: j1 m4-7 */                                                    \
    PHASE_BAR();                                                              \
    _Pragma("unroll") for (int m = 0; m < 4; ++m)                             \
        ag[m] = *(const s16x8*)(Ab + ard[4 + m] + (co0 ^ 64));                \
    asm volatile("s_waitcnt lgkmcnt(0)" ::: "memory");                        \
    __builtin_amdgcn_sched_barrier(0);                                        \
    __builtin_amdgcn_s_setprio(1);                                            \
    _Pragma("unroll") for (int n = 0; n < 4; ++n)                             \
      _Pragma("unroll") for (int m = 0; m < 4; ++m)                           \
          acc[4 + m][n] = __builtin_amdgcn_mfma_f32_16x16x32_bf16(            \
              ag[m], wf[n], acc[4 + m][n], 0, 0, 0);                          \
    __builtin_amdgcn_s_setprio(0);                                            \
  }

  for (int tt = 0; tt < NT; tt += 2) {
    GSTEP(0, tt);
    GSTEP(1, tt + 1);
  }
#undef GSTEP

  // Drain all in-flight DMA/loads before epilogue.
  asm volatile("s_waitcnt vmcnt(0) lgkmcnt(0)" ::: "memory");
  __builtin_amdgcn_sched_barrier(0);

  // C/D frag: col = lane&15, row = (lane>>4)*4 + j
  float* Pp = Ppart + ((size_t)(ks * 2 + p) * BATCH + mt * 256) * H1;
  const int r0 = wm * 128 + lkq * 4;
  const int c0 = nt * 256 + wn * 64 + lrow;
#pragma unroll
  for (int m = 0; m < 8; ++m)
#pragma unroll
    for (int n = 0; n < 4; ++n) {
      float* dst = Pp + (size_t)(r0 + m * 16) * H1 + c0 + n * 16;
#pragma unroll
      for (int j = 0; j < 4; ++j) dst[(size_t)j * H1] = acc[m][n][j];
    }
}

// ---------------------------------------------------------------------------
// Kernel 2: reduce split-K partials + bias + clip[0,1] -> combined bf16
// ---------------------------------------------------------------------------
__global__ __launch_bounds__(256)
void ft_reduce_kernel(const float* __restrict__ Ppart,
                      const float* __restrict__ ftb,
                      unsigned short* __restrict__ comb) {
  const size_t gid = (size_t)blockIdx.x * 256 + threadIdx.x;  // 2*B*H1/4
  const int    pp  = (int)(gid / (BATCH * H1 / 4));
  const size_t rem = gid % (BATCH * H1 / 4);
  const int    row = (int)(rem / (H1 / 4));
  const int    n4  = (int)(rem % (H1 / 4)) * 4;

  f32x4 s = (f32x4){0.f, 0.f, 0.f, 0.f};
#pragma unroll
  for (int ks = 0; ks < KS; ++ks)
    s += *(const f32x4*)(Ppart + ((size_t)(ks * 2 + pp) * BATCH + row) * H1 + n4);
  const f32x4 bv = *(const f32x4*)(ftb + n4);
  s += bv;
  s.x = fminf(fmaxf(s.x, 0.f), 1.f);
  s.y = fminf(fmaxf(s.y, 0.f), 1.f);
  s.z = fminf(fmaxf(s.z, 0.f), 1.f);
  s.w = fminf(fmaxf(s.w, 0.f), 1.f);

  u32x2 o;
  o.x = bfpack2(s.x, s.y);
  o.y = bfpack2(s.z, s.w);
  *(u32x2*)(comb + (size_t)row * 1024 + pp * H1 + n4) = o;
}

// ---------------------------------------------------------------------------
// Kernel 3: fc1 (bf16 MFMA) + relu + fc2 dot + bias -> out FLOAT32 [4096]
// ---------------------------------------------------------------------------
__global__ __launch_bounds__(256)
void fc_kernel(const unsigned short* __restrict__ comb,
               const float* __restrict__ w1, const float* __restrict__ b1,
               const float* __restrict__ w2, const float* __restrict__ b2,
               float* __restrict__ out) {
  __shared__ char smem[40960];  // 2 x (A 4KB + W 16KB)
  __shared__ float rowsum[64];

  const int tid = threadIdx.x;
  const int bm  = blockIdx.x;  // 64 blocks of 64 rows
  if (tid < 64) rowsum[tid] = 0.f;

  const int a_row = tid >> 2, a_kq = tid & 3;
  const unsigned short* aptr = comb + (size_t)(bm * 64 + a_row) * 1024 + a_kq * 8;
  const float* wptr = w1 + (size_t)a_row * 1024 + a_kq * 8;

  u32x4 raA;
  f32x4 rw0[4], rw1[4];
  auto issue = [&](int t) {
    raA = *(const u32x4*)(aptr + t * 32);
    const float* wp = wptr + t * 32;
#pragma unroll
    for (int s = 0; s < 4; ++s) {
      rw0[s] = *(const f32x4*)(wp + (size_t)s * 64 * 1024);
      rw1[s] = *(const f32x4*)(wp + (size_t)s * 64 * 1024 + 4);
    }
  };

  const int aoff_w = lds_swz(a_row, a_kq * 16);
  int woff_w[4];
#pragma unroll
  for (int s = 0; s < 4; ++s)
    woff_w[s] = 4096 + lds_swz(s * 64 + a_row, a_kq * 16);

  auto cvtwrite = [&](int b) {
    char* base = smem + b * 20480;
    *(u32x4*)(base + aoff_w) = raA;
#pragma unroll
    for (int s = 0; s < 4; ++s) {
      u32x4 wv;
      wv.x = bfpack2(rw0[s].x, rw0[s].y); wv.y = bfpack2(rw0[s].z, rw0[s].w);
      wv.z = bfpack2(rw1[s].x, rw1[s].y); wv.w = bfpack2(rw1[s].z, rw1[s].w);
      *(u32x4*)(base + woff_w[s]) = wv;
    }
  };

  const int lane = tid & 63, wn = tid >> 6;
  const int lrow = lane & 15, lkb = (lane >> 4) * 16;
  int a_off[4], b_off[4];
#pragma unroll
  for (int m = 0; m < 4; ++m) a_off[m] = lds_swz(m * 16 + lrow, lkb);
#pragma unroll
  for (int n = 0; n < 4; ++n) b_off[n] = 4096 + lds_swz(wn * 64 + n * 16 + lrow, lkb);

  f32x4 acc[4][4];
#pragma unroll
  for (int m = 0; m < 4; ++m)
#pragma unroll
    for (int n = 0; n < 4; ++n) acc[m][n] = (f32x4){0.f, 0.f, 0.f, 0.f};

  issue(0);
  for (int t = 0; t < 32; ++t) {
    const int b = t & 1;
    cvtwrite(b);
    if (t + 1 < 32) issue(t + 1);
    asm volatile("s_waitcnt lgkmcnt(0)" ::: "memory");
    __builtin_amdgcn_sched_barrier(0);
    __builtin_amdgcn_s_barrier();
    __builtin_amdgcn_sched_barrier(0);
    char* base = smem + b * 20480;
    s16x8 af[4];
#pragma unroll
    for (int m = 0; m < 4; ++m) af[m] = *(const s16x8*)(base + a_off[m]);
#pragma unroll
    for (int n = 0; n < 4; ++n) {
      s16x8 bfn = *(const s16x8*)(base + b_off[n]);
#pragma unroll
      for (int m = 0; m < 4; ++m)
        acc[m][n] = __builtin_amdgcn_mfma_f32_16x16x32_bf16(af[m], bfn, acc[m][n], 0, 0, 0);
    }
  }

  float b1v[4], w2v[4];
#pragma unroll
  for (int n = 0; n < 4; ++n) {
    const int col = wn * 64 + n * 16 + lrow;
    b1v[n] = b1[col];
    w2v[n] = w2[col];
  }
#pragma unroll
  for (int m = 0; m < 4; ++m)
#pragma unroll
    for (int j = 0; j < 4; ++j) {
      float v = 0.f;
#pragma unroll
      for (int n = 0; n < 4; ++n) {
        float x = acc[m][n][j] + b1v[n];
        x = fmaxf(x, 0.f);
        v += x * w2v[n];
      }
#pragma unroll
      for (int d = 1; d < 16; d <<= 1) v += __shfl_xor(v, d, 64);
      if ((lane & 15) == 0)
        atomicAdd(&rowsum[m * 16 + (lane >> 4) * 4 + j], v);
    }
  __syncthreads();
  if (tid < 64) {
    out[bm * 64 + tid] = rowsum[tid] + b2[0];  // f32 output
  }
}

// ---------------------------------------------------------------------------
extern "C" void kernel_launch(void* const* d_in, const int* in_sizes, int n_in,
                              void* d_out, int out_size, void* d_ws, size_t ws_size,
                              hipStream_t stream) {
  const float* whiteF = (const float*)d_in[0];
  const float* blackF = (const float*)d_in[1];
  const float* ftw    = (const float*)d_in[2];
  const float* ftb    = (const float*)d_in[3];
  const float* w1     = (const float*)d_in[4];
  const float* b1     = (const float*)d_in[5];
  const float* w2     = (const float*)d_in[6];
  const float* b2     = (const float*)d_in[7];

  char* wbf = (char*)d_ws;                                   // 41,943,040 B
  const size_t wbf_bytes   = (size_t)NT64 * WIMG;
  const size_t ppart_bytes = (size_t)KS * 2 * BATCH * H1 * sizeof(float);
  float* Ppart = (float*)((char*)d_ws + wbf_bytes);
  unsigned short* comb = (unsigned short*)((char*)d_ws + wbf_bytes + ppart_bytes);
  float* outp = (float*)d_out;

  hipLaunchKernelGGL(wcvt_kernel, dim3(NT64), dim3(512), 0, stream, ftw, wbf);
  hipLaunchKernelGGL(ft_gemm_kernel, dim3(256), dim3(512), 0, stream,
                     whiteF, blackF, wbf, Ppart);
  hipLaunchKernelGGL(ft_reduce_kernel, dim3((2 * BATCH * H1 / 4) / 256), dim3(256),
                     0, stream, Ppart, ftb, comb);
  hipLaunchKernelGGL(fc_kernel, dim3(BATCH / 64), dim3(256), 0, stream,
                     comb, w1, b1, w2, b2, outp);
}

// Round 13
// 638.181 us; speedup vs baseline: 1.6488x; 1.6488x over previous
//
#include <hip/hip_runtime.h>
#include <stdint.h>

#define BATCH 4096
#define FEAT  40960
#define H1    512
#define KS    4
#define KCHUNK (FEAT / KS)     // 10240
#define NSTEPS (KCHUNK / 32)   // 320 micro (K=32) tiles per chunk
#define NMACRO (KCHUNK / 128)  // 80 macro (K=128) slabs per chunk
#define NTILES (FEAT / 32)     // 1280 global micro tiles
#define WTILE  32768           // bytes per fragment-major W micro-tile

typedef float f32x4 __attribute__((ext_vector_type(4)));
typedef short s16x8 __attribute__((ext_vector_type(8)));
typedef unsigned int u32x2 __attribute__((ext_vector_type(2)));
typedef unsigned int u32x4 __attribute__((ext_vector_type(4)));

// round-to-nearest-even f32 -> bf16, packed pair (lo in low 16 bits)
__device__ __forceinline__ unsigned bfpack2(float lo, float hi) {
  unsigned a = __float_as_uint(lo);
  unsigned b = __float_as_uint(hi);
  a += 0x7FFFu + ((a >> 16) & 1u);
  b += 0x7FFFu + ((b >> 16) & 1u);
  return (a >> 16) | (b & 0xFFFF0000u);
}

// HW packed f32->bf16 (RTNE): dst.lo16 = cvt(lo), dst.hi16 = cvt(hi)
__device__ __forceinline__ unsigned cvtpk(float lo, float hi) {
  unsigned r;
  asm("v_cvt_pk_bf16_f32 %0, %1, %2" : "=v"(r) : "v"(lo), "v"(hi));
  return r;
}

// legacy swizzle for fc kernel's 64B-row tiles (proven r3-r9)
__device__ __forceinline__ int lds_swz(int r, int cb) {
  return (r << 6) + (cb ^ (((r >> 1) & 3) << 4));
}

// async global->LDS, 16B/lane; LDS dest = wave-uniform base + lane*16.
__device__ __forceinline__ void glds16(const void* g, void* l) {
  __builtin_amdgcn_global_load_lds(
      (const __attribute__((address_space(1))) unsigned*)g,
      (__attribute__((address_space(3))) unsigned*)l, 16, 0, 0);
}

#define SFENCE() __builtin_amdgcn_sched_barrier(0)

// ---------------------------------------------------------------------------
// Kernel 0: one-time ftw f32 -> bf16 FRAGMENT-MAJOR image (r7, proven):
// wbf[T][nb*4+f][lane][8 bf16]: frag chunk (nb*4+f) is one contiguous 1KB;
// lane l holds W[row nb*64+f*16+(l&15)][k (l>>4)*8..+8].
// ---------------------------------------------------------------------------
__global__ __launch_bounds__(512)
void wcvt_kernel(const float* __restrict__ ftw, char* __restrict__ wbf) {
  const int T = blockIdx.x;  // 0..NTILES-1
  const int tid = threadIdx.x;
  const int c  = tid & 7;
  const int r0 = tid >> 3;
#pragma unroll
  for (int pass = 0; pass < 8; ++pass) {
    const int r = pass * 64 + r0;
    const float* src = ftw + (size_t)r * FEAT + T * 32 + c * 4;
    f32x4 v = *(const f32x4*)src;
    u32x2 o;
    o.x = bfpack2(v.x, v.y);
    o.y = bfpack2(v.z, v.w);
    const int nb = r >> 6, f = (r >> 4) & 3, lr = r & 15;
    const int l = (c >> 1) * 16 + lr;
    *(u32x2*)(wbf + (size_t)T * WTILE + ((nb * 4 + f) << 10) + l * 16 +
              (c & 1) * 8) = o;
  }
}

// ---------------------------------------------------------------------------
// Kernel 1: ft GEMM, split-K partials. MACRO-K=128 / A-f32-DMA design.
// BM=64 BN=512, 512 thr = 8 waves (1M x 8N), wave tile 64x64, acc 64 AGPR.
// A: DMA'd to LDS as f32 in 512B-contiguous-per-row chunks (DRAM-granule
//    fix for the 1.6 TB/s six-round plateau); f32->bf16 cvt on LDS->reg
//    path (v_cvt_pk). Slab dbuf 2x32KB = all the LDS -> 2 blocks/CU.
//    LDS reads swizzled unit^=(row&7): uniform bank load (conflict-free);
//    same permutation applied to the DMA global source (rule #21).
// W: r7-proven register path, single-set wb[4], refilled per micro after
//    MFMA consumption (WAR keeps order; L2 latency hides under the micro).
// Sync: 1 barrier/macro (80 total). vmcnt ledger: macro-top invariant
//    [W:4]; A parts issued 1/micro (2-micro cover each); macro-end
//    vmcnt(4) completes A parts before the barrier.
// ---------------------------------------------------------------------------
__global__ __launch_bounds__(512, 4)
void ft_gemm_kernel(const float* __restrict__ whiteF,
                    const float* __restrict__ blackF,
                    const char* __restrict__ wbf,
                    float* __restrict__ Ppart) {
  __shared__ char smem[65536];  // A f32 slabs @0, @32768

  const int tid = threadIdx.x, bid = blockIdx.x;
  const int wgid = (bid & 7) * 64 + (bid >> 3);  // XCD-chunked, bijective
  const int ks = wgid >> 7;
  const int p  = (wgid >> 6) & 1;
  const int mt = wgid & 63;

  const float* Ag =
      (p == 0 ? whiteF : blackF) + (size_t)(mt * 64) * FEAT + ks * KCHUNK;
  const char* Agc = (const char*)Ag;

  const int lane = tid & 63, wave = tid >> 6;
  const int lrow = lane & 15, lkq = lane >> 4;

  // A-DMA part j: rows wave*8+2j+(lane>>5); lane covers 16B unit c of the
  // row's 512B macro span, pre-swizzled c^(row&7) to match the read side.
  unsigned aoff[4];  // byte offset from Ag; invariant: points at (T+1)*512
  int adst[4];       // LDS dest base (wave-uniform, slab-relative)
  const int c31 = lane & 31;
#pragma unroll
  for (int j = 0; j < 4; ++j) {
    const int rr = wave * 8 + 2 * j + (lane >> 5);
    aoff[j] = (unsigned)rr * (FEAT * 4u) + (unsigned)((c31 ^ (rr & 7)) << 4);
    adst[j] = (wave * 8 + 2 * j) * 512;
  }

  // af ds_read addrs: frag m row m*16+lrow; unit (lkq*2+i)^(lrow&7);
  // + compile-time offset (slab*32768 + micro*128) at the read site.
  int adA[4][2];
#pragma unroll
  for (int m = 0; m < 4; ++m)
#pragma unroll
    for (int i = 0; i < 2; ++i)
      adA[m][i] = (m * 16 + lrow) * 512 + ((((lkq << 1) | i) ^ (lrow & 7)) << 4);

  // W fragment source (per-wave slice of fragment-major image)
  const char* wptr =
      wbf + (size_t)(ks * NSTEPS) * WTILE + (wave << 12) + lane * 16;

  f32x4 acc[4][4];
#pragma unroll
  for (int m = 0; m < 4; ++m)
#pragma unroll
    for (int n = 0; n < 4; ++n) acc[m][n] = (f32x4){0.f, 0.f, 0.f, 0.f};

  u32x4 wb[4];

  // ---- prologue: slab0 DMA (4, oldest) | W(micro0) (4) | vmcnt(4) | barrier
#pragma unroll
  for (int j = 0; j < 4; ++j) glds16(Agc + aoff[j], smem + adst[j]);
  SFENCE();  // keep A-DMA older than W loads in the vm queue
#pragma unroll
  for (int n = 0; n < 4; ++n) wb[n] = *(const u32x4*)(wptr + (n << 10));
#pragma unroll
  for (int j = 0; j < 4; ++j) aoff[j] += 512;  // now -> macro 1
  asm volatile("s_waitcnt vmcnt(4)" ::: "memory");  // slab0 complete
  SFENCE();
  __builtin_amdgcn_s_barrier();
  SFENCE();

// one micro: af reads+cvt, 16 MFMA, W refill, A part (order per JM)
#define MICRO(B, JM, T)                                                       \
  {                                                                           \
    s16x8 af[4];                                                              \
    _Pragma("unroll") for (int m = 0; m < 4; ++m) {                           \
      f32x4 lo = *(const f32x4*)(smem + adA[m][0] + (B) * 32768 + (JM) * 128);\
      f32x4 hi = *(const f32x4*)(smem + adA[m][1] + (B) * 32768 + (JM) * 128);\
      u32x4 cv;                                                               \
      cv.x = cvtpk(lo.x, lo.y); cv.y = cvtpk(lo.z, lo.w);                     \
      cv.z = cvtpk(hi.x, hi.y); cv.w = cvtpk(hi.z, hi.w);                     \
      af[m] = __builtin_bit_cast(s16x8, cv);                                  \
    }                                                                         \
    _Pragma("unroll") for (int n = 0; n < 4; ++n)                             \
      _Pragma("unroll") for (int m = 0; m < 4; ++m)                           \
          acc[m][n] = __builtin_amdgcn_mfma_f32_16x16x32_bf16(                \
              af[m], __builtin_bit_cast(s16x8, wb[n]), acc[m][n], 0, 0, 0);   \
    if ((JM) < 3) { /* W refill (WAR after MFMA), then A part JM */           \
      const char* wsp = wptr + (size_t)(4 * (T) + (JM) + 1) * WTILE;          \
      _Pragma("unroll") for (int n = 0; n < 4; ++n)                           \
          wb[n] = *(const u32x4*)(wsp + (n << 10));                           \
      glds16(Agc + aoff[JM], smem + (((B) ^ 1) * 32768) + adst[JM]);          \
    } else { /* A part 3 FIRST (macro-end vmcnt(4) must complete it) */       \
      glds16(Agc + aoff[3], smem + (((B) ^ 1) * 32768) + adst[3]);            \
      SFENCE();                                                               \
      const char* wsp = wptr + (size_t)(4 * (T) + 4) * WTILE;                 \
      _Pragma("unroll") for (int n = 0; n < 4; ++n)                           \
          wb[n] = *(const u32x4*)(wsp + (n << 10));                           \
    }                                                                         \
  }

#define MACRO(B, T)                                                           \
  {                                                                           \
    MICRO(B, 0, T);                                                           \
    MICRO(B, 1, T);                                                           \
    MICRO(B, 2, T);                                                           \
    MICRO(B, 3, T);                                                           \
    asm volatile("s_waitcnt vmcnt(4)" ::: "memory"); /* A parts done */       \
    SFENCE();                                                                 \
    __builtin_amdgcn_s_barrier();                                             \
    SFENCE();                                                                 \
    const unsigned adv = ((T) + 2 < NMACRO) ? 512u : 0u;                      \
    _Pragma("unroll") for (int j = 0; j < 4; ++j) aoff[j] += adv;             \
  }

  for (int TT = 0; TT < NMACRO; TT += 2) {
    MACRO(0, TT);
    MACRO(1, TT + 1);
  }
#undef MACRO
#undef MICRO

  // Drain all in-flight DMA/loads before epilogue (LDS may be reallocated).
  asm volatile("s_waitcnt vmcnt(0) lgkmcnt(0)" ::: "memory");
  SFENCE();

  // C/D frag: col = lane&15, row = (lane>>4)*4 + j
  float* Pp = Ppart + ((size_t)(ks * 2 + p) * BATCH + mt * 64) * H1;
  const int r0 = lkq * 4;
  const int c0 = wave * 64 + lrow;
#pragma unroll
  for (int m = 0; m < 4; ++m)
#pragma unroll
    for (int n = 0; n < 4; ++n) {
      float* dst = Pp + (size_t)(r0 + m * 16) * H1 + c0 + n * 16;
#pragma unroll
      for (int j = 0; j < 4; ++j) dst[(size_t)j * H1] = acc[m][n][j];
    }
}

// ---------------------------------------------------------------------------
// Kernel 2: reduce split-K partials + bias + clip[0,1] -> combined bf16
// ---------------------------------------------------------------------------
__global__ __launch_bounds__(256)
void ft_reduce_kernel(const float* __restrict__ Ppart,
                      const float* __restrict__ ftb,
                      unsigned short* __restrict__ comb) {
  const size_t gid = (size_t)blockIdx.x * 256 + threadIdx.x;  // 2*B*H1/4
  const int    pp  = (int)(gid / (BATCH * H1 / 4));
  const size_t rem = gid % (BATCH * H1 / 4);
  const int    row = (int)(rem / (H1 / 4));
  const int    n4  = (int)(rem % (H1 / 4)) * 4;

  f32x4 s = (f32x4){0.f, 0.f, 0.f, 0.f};
#pragma unroll
  for (int ks = 0; ks < KS; ++ks)
    s += *(const f32x4*)(Ppart + ((size_t)(ks * 2 + pp) * BATCH + row) * H1 + n4);
  const f32x4 bv = *(const f32x4*)(ftb + n4);
  s += bv;
  s.x = fminf(fmaxf(s.x, 0.f), 1.f);
  s.y = fminf(fmaxf(s.y, 0.f), 1.f);
  s.z = fminf(fmaxf(s.z, 0.f), 1.f);
  s.w = fminf(fmaxf(s.w, 0.f), 1.f);

  u32x2 o;
  o.x = bfpack2(s.x, s.y);
  o.y = bfpack2(s.z, s.w);
  *(u32x2*)(comb + (size_t)row * 1024 + pp * H1 + n4) = o;
}

// ---------------------------------------------------------------------------
// Kernel 3: fc1 (bf16 MFMA) + relu + fc2 dot + bias -> out FLOAT32 [4096]
// ---------------------------------------------------------------------------
__global__ __launch_bounds__(256)
void fc_kernel(const unsigned short* __restrict__ comb,
               const float* __restrict__ w1, const float* __restrict__ b1,
               const float* __restrict__ w2, const float* __restrict__ b2,
               float* __restrict__ out) {
  __shared__ char smem[40960];  // 2 x (A 4KB + W 16KB)
  __shared__ float rowsum[64];

  const int tid = threadIdx.x;
  const int bm  = blockIdx.x;  // 64 blocks of 64 rows
  if (tid < 64) rowsum[tid] = 0.f;

  const int a_row = tid >> 2, a_kq = tid & 3;
  const unsigned short* aptr = comb + (size_t)(bm * 64 + a_row) * 1024 + a_kq * 8;
  const float* wptr = w1 + (size_t)a_row * 1024 + a_kq * 8;

  u32x4 raA;
  f32x4 rw0[4], rw1[4];
  auto issue = [&](int t) {
    raA = *(const u32x4*)(aptr + t * 32);
    const float* wp = wptr + t * 32;
#pragma unroll
    for (int s = 0; s < 4; ++s) {
      rw0[s] = *(const f32x4*)(wp + (size_t)s * 64 * 1024);
      rw1[s] = *(const f32x4*)(wp + (size_t)s * 64 * 1024 + 4);
    }
  };

  const int aoff_w = lds_swz(a_row, a_kq * 16);
  int woff_w[4];
#pragma unroll
  for (int s = 0; s < 4; ++s)
    woff_w[s] = 4096 + lds_swz(s * 64 + a_row, a_kq * 16);

  auto cvtwrite = [&](int b) {
    char* base = smem + b * 20480;
    *(u32x4*)(base + aoff_w) = raA;
#pragma unroll
    for (int s = 0; s < 4; ++s) {
      u32x4 wv;
      wv.x = bfpack2(rw0[s].x, rw0[s].y); wv.y = bfpack2(rw0[s].z, rw0[s].w);
      wv.z = bfpack2(rw1[s].x, rw1[s].y); wv.w = bfpack2(rw1[s].z, rw1[s].w);
      *(u32x4*)(base + woff_w[s]) = wv;
    }
  };

  const int lane = tid & 63, wn = tid >> 6;
  const int lrow = lane & 15, lkb = (lane >> 4) * 16;
  int a_off[4], b_off[4];
#pragma unroll
  for (int m = 0; m < 4; ++m) a_off[m] = lds_swz(m * 16 + lrow, lkb);
#pragma unroll
  for (int n = 0; n < 4; ++n) b_off[n] = 4096 + lds_swz(wn * 64 + n * 16 + lrow, lkb);

  f32x4 acc[4][4];
#pragma unroll
  for (int m = 0; m < 4; ++m)
#pragma unroll
    for (int n = 0; n < 4; ++n) acc[m][n] = (f32x4){0.f, 0.f, 0.f, 0.f};

  issue(0);
  for (int t = 0; t < 32; ++t) {
    const int b = t & 1;
    cvtwrite(b);
    if (t + 1 < 32) issue(t + 1);
    asm volatile("s_waitcnt lgkmcnt(0)" ::: "memory");
    __builtin_amdgcn_sched_barrier(0);
    __builtin_amdgcn_s_barrier();
    __builtin_amdgcn_sched_barrier(0);
    char* base = smem + b * 20480;
    s16x8 af[4];
#pragma unroll
    for (int m = 0; m < 4; ++m) af[m] = *(const s16x8*)(base + a_off[m]);
#pragma unroll
    for (int n = 0; n < 4; ++n) {
      s16x8 bfn = *(const s16x8*)(base + b_off[n]);
#pragma unroll
      for (int m = 0; m < 4; ++m)
        acc[m][n] = __builtin_amdgcn_mfma_f32_16x16x32_bf16(af[m], bfn, acc[m][n], 0, 0, 0);
    }
  }

  float b1v[4], w2v[4];
#pragma unroll
  for (int n = 0; n < 4; ++n) {
    const int col = wn * 64 + n * 16 + lrow;
    b1v[n] = b1[col];
    w2v[n] = w2[col];
  }
#pragma unroll
  for (int m = 0; m < 4; ++m)
#pragma unroll
    for (int j = 0; j < 4; ++j) {
      float v = 0.f;
#pragma unroll
      for (int n = 0; n < 4; ++n) {
        float x = acc[m][n][j] + b1v[n];
        x = fmaxf(x, 0.f);
        v += x * w2v[n];
      }
#pragma unroll
      for (int d = 1; d < 16; d <<= 1) v += __shfl_xor(v, d, 64);
      if ((lane & 15) == 0)
        atomicAdd(&rowsum[m * 16 + (lane >> 4) * 4 + j], v);
    }
  __syncthreads();
  if (tid < 64) {
    out[bm * 64 + tid] = rowsum[tid] + b2[0];  // f32 output
  }
}

// ---------------------------------------------------------------------------
extern "C" void kernel_launch(void* const* d_in, const int* in_sizes, int n_in,
                              void* d_out, int out_size, void* d_ws, size_t ws_size,
                              hipStream_t stream) {
  const float* whiteF = (const float*)d_in[0];
  const float* blackF = (const float*)d_in[1];
  const float* ftw    = (const float*)d_in[2];
  const float* ftb    = (const float*)d_in[3];
  const float* w1     = (const float*)d_in[4];
  const float* b1     = (const float*)d_in[5];
  const float* w2     = (const float*)d_in[6];
  const float* b2     = (const float*)d_in[7];

  char* wbf = (char*)d_ws;  // 41,943,040 B
  const size_t wbf_bytes   = (size_t)NTILES * WTILE;
  const size_t ppart_bytes = (size_t)KS * 2 * BATCH * H1 * sizeof(float);
  float* Ppart = (float*)((char*)d_ws + wbf_bytes);
  unsigned short* comb = (unsigned short*)((char*)d_ws + wbf_bytes + ppart_bytes);
  float* outp = (float*)d_out;

  hipLaunchKernelGGL(wcvt_kernel, dim3(NTILES), dim3(512), 0, stream, ftw, wbf);
  hipLaunchKernelGGL(ft_gemm_kernel, dim3(512), dim3(512), 0, stream,
                     whiteF, blackF, wbf, Ppart);
  hipLaunchKernelGGL(ft_reduce_kernel, dim3((2 * BATCH * H1 / 4) / 256), dim3(256),
                     0, stream, Ppart, ftb, comb);
  hipLaunchKernelGGL(fc_kernel, dim3(BATCH / 64), dim3(256), 0, stream,
                     comb, w1, b1, w2, b2, outp);
}